// Round 14
// baseline (387.806 us; speedup 1.0000x reference)
//
#include <hip/hip_runtime.h>
#include <hip/hip_fp16.h>
#include <math.h>

#define N_NODES 50000
#define E_EDGES 800000
#define E_TOT   850000   // E_EDGES + N_NODES self loops
#define F_IN    128
#define C1      256      // HEADS*HID
#define NCLS    47
#define H2S     48       // padded stride for H2 (47 -> 48)
#define NEG     0.2f
#define SCAN_B  196      // ceil(50000/256)
#define HEP     264      // LDS HE row stride in halves (256 + 8 pad; 528B, 16B-aligned)

// k_setup block ranges
#define SB_CNT  3321     // ceil(850000/256)      : k_count
#define SB_PX   6250     // 50000*128/4/256       : prepx
#define SB_W1   16       // 4096/256              : prepw1f
#define SB_W2   6        // 1536/256              : prepw2f

typedef _Float16 f16x8 __attribute__((ext_vector_type(8)));
typedef float    f32x4 __attribute__((ext_vector_type(4)));

// ---------------- fused setup: count + x->fp16 + W1/W2 fragment packs ----------

__global__ void k_setup(const int* __restrict__ ei, int* __restrict__ deg,
                        const float* __restrict__ x, __half* __restrict__ xh,
                        const float* __restrict__ W1, uint4* __restrict__ W1f,
                        const float* __restrict__ W2, uint4* __restrict__ W2f) {
    int bid = blockIdx.x;
    if (bid < SB_CNT) {                               // ---- edge-dst histogram
        int i = bid * 256 + threadIdx.x;
        if (i >= E_TOT) return;
        int dst = (i < E_EDGES) ? ei[E_EDGES + i] : (i - E_EDGES);
        atomicAdd(&deg[dst], 1);
        return;
    }
    bid -= SB_CNT;
    if (bid < SB_PX) {                                // ---- x -> fp16 (float4 units)
        int i = bid * 256 + threadIdx.x;
        float4 v = ((const float4*)x)[i];
        ushort4 p;
        p.x = __half_as_ushort(__float2half_rn(v.x));
        p.y = __half_as_ushort(__float2half_rn(v.y));
        p.z = __half_as_ushort(__float2half_rn(v.z));
        p.w = __half_as_ushort(__float2half_rn(v.w));
        ((ushort4*)xh)[i] = p;
        return;
    }
    bid -= SB_PX;
    if (bid < SB_W1) {                                // ---- W1 B-fragments
        int t = bid * 256 + threadIdx.x;              // t < 4096
        int f = t >> 8, ks = (t >> 6) & 3, lane = t & 63;
        int c  = f * 16 + (lane & 15);
        int kb = ks * 32 + ((lane >> 4) << 3);
        unsigned short h[8];
        #pragma unroll
        for (int j = 0; j < 8; j++)
            h[j] = __half_as_ushort(__float2half_rn(W1[(size_t)(kb + j) * C1 + c]));
        W1f[t] = make_uint4((unsigned)h[0] | ((unsigned)h[1] << 16),
                            (unsigned)h[2] | ((unsigned)h[3] << 16),
                            (unsigned)h[4] | ((unsigned)h[5] << 16),
                            (unsigned)h[6] | ((unsigned)h[7] << 16));
        return;
    }
    bid -= SB_W1;
    {                                                 // ---- W2 B-fragments (padded c>=47)
        int t = bid * 256 + threadIdx.x;              // t < 1536
        int f = t >> 9, ks = (t >> 6) & 7, lane = t & 63;
        int c  = f * 16 + (lane & 15);
        int kb = ks * 32 + ((lane >> 4) << 3);
        unsigned short h[8];
        #pragma unroll
        for (int j = 0; j < 8; j++) {
            float v = (c < NCLS) ? W2[(size_t)(kb + j) * NCLS + c] : 0.f;
            h[j] = __half_as_ushort(__float2half_rn(v));
        }
        W2f[t] = make_uint4((unsigned)h[0] | ((unsigned)h[1] << 16),
                            (unsigned)h[2] | ((unsigned)h[3] << 16),
                            (unsigned)h[4] | ((unsigned)h[5] << 16),
                            (unsigned)h[6] | ((unsigned)h[7] << 16));
    }
}

// ---------------- CSR scan (3-pass) + scatter ----------------

__global__ void k_scan_blk(const int* __restrict__ deg, int* __restrict__ blksum) {
    __shared__ int ws[4];
    int i = blockIdx.x * 256 + threadIdx.x;
    int v = (i < N_NODES) ? deg[i] : 0;
    int lane = threadIdx.x & 63, w = threadIdx.x >> 6;
    #pragma unroll
    for (int off = 32; off; off >>= 1) v += __shfl_xor(v, off);
    if (lane == 0) ws[w] = v;
    __syncthreads();
    if (threadIdx.x == 0) blksum[blockIdx.x] = ws[0] + ws[1] + ws[2] + ws[3];
}

__global__ void k_scan_top(const int* __restrict__ blksum, int* __restrict__ blkoff) {
    __shared__ int ws[4];
    int tid = threadIdx.x, lane = tid & 63, w = tid >> 6;
    int v = (tid < SCAN_B) ? blksum[tid] : 0;
    int sc = v;
    #pragma unroll
    for (int off = 1; off < 64; off <<= 1) {
        int t = __shfl_up(sc, off);
        if (lane >= off) sc += t;
    }
    if (lane == 63) ws[w] = sc;
    __syncthreads();
    if (tid == 0) { int a = 0; for (int t = 0; t < 4; t++) { int u = ws[t]; ws[t] = a; a += u; } }
    __syncthreads();
    if (tid < SCAN_B) blkoff[tid] = sc + ws[w] - v;   // exclusive
}

__global__ void k_scan_fin(const int* __restrict__ deg, const int* __restrict__ blkoff,
                           int* __restrict__ row_ptr, int* __restrict__ cursor) {
    __shared__ int ws[4];
    int i = blockIdx.x * 256 + threadIdx.x;
    int v = (i < N_NODES) ? deg[i] : 0;
    int lane = threadIdx.x & 63, w = threadIdx.x >> 6;
    int sc = v;
    #pragma unroll
    for (int off = 1; off < 64; off <<= 1) {
        int t = __shfl_up(sc, off);
        if (lane >= off) sc += t;
    }
    if (lane == 63) ws[w] = sc;
    __syncthreads();
    if (threadIdx.x == 0) { int a = 0; for (int t = 0; t < 4; t++) { int u = ws[t]; ws[t] = a; a += u; } }
    __syncthreads();
    int incl = sc + ws[w] + blkoff[blockIdx.x];
    if (i < N_NODES) {
        row_ptr[i + 1] = incl;
        cursor[i]      = incl - v;
    }
    if (i == 0) row_ptr[0] = 0;
}

__global__ void k_scatter(const int* __restrict__ ei, int* __restrict__ cursor,
                          int* __restrict__ csr_src) {
    int i = blockIdx.x * 256 + threadIdx.x;
    if (i >= E_TOT) return;
    int src, dst;
    if (i < E_EDGES) { src = ei[i]; dst = ei[E_EDGES + i]; }
    else             { src = dst = i - E_EDGES; }
    int pos = atomicAdd(&cursor[dst], 1);
    csr_src[pos] = src;
}

// ---------------- Layer 1: GEMM (x @ W1) via MFMA + attention logits ----------
// One wave per 16 rows. 64 mfma_f32_16x16x32_f16 per wave.
// D (m89-verified): col = f*16 + (lane&15), row = (lane>>4)*4 + reg.

__global__ void __launch_bounds__(64)
k_gemm1(const __half* __restrict__ xh, const uint4* __restrict__ W1f,
        const float* __restrict__ a_src1, const float* __restrict__ a_dst1,
        __half* __restrict__ H1h, float* __restrict__ al_s, float* __restrict__ al_d) {
    int lane = threadIdx.x;
    int n0 = blockIdx.x * 16;
    const __half* aptr = xh + (size_t)(n0 + (lane & 15)) * F_IN + ((lane >> 4) << 3);
    const f16x8* bptr = (const f16x8*)W1f;
    f32x4 acc[16];
    #pragma unroll
    for (int f = 0; f < 16; f++) acc[f] = (f32x4){0.f, 0.f, 0.f, 0.f};
    #pragma unroll
    for (int ks = 0; ks < 4; ks++) {
        f16x8 a = *(const f16x8*)(aptr + ks * 32);
        #pragma unroll
        for (int f = 0; f < 16; f++) {
            f16x8 b = bptr[(f * 4 + ks) * 64 + lane];
            acc[f] = __builtin_amdgcn_mfma_f32_16x16x32_f16(a, b, acc[f], 0, 0, 0);
        }
    }
    int col = lane & 15;
    int g4  = (lane >> 4) * 4;
    float asf[16], adf[16];
    #pragma unroll
    for (int f = 0; f < 16; f++) {
        asf[f] = a_src1[f * 16 + col];
        adf[f] = a_dst1[f * 16 + col];
    }
    #pragma unroll
    for (int reg = 0; reg < 4; reg++) {
        int n = n0 + g4 + reg;
        float vs[4] = {0.f, 0.f, 0.f, 0.f};
        float vd[4] = {0.f, 0.f, 0.f, 0.f};
        #pragma unroll
        for (int f = 0; f < 16; f++) {
            float v = acc[f][reg];
            H1h[(size_t)n * C1 + f * 16 + col] = __float2half_rn(v);
            vs[f >> 2] += v * asf[f];
            vd[f >> 2] += v * adf[f];
        }
        #pragma unroll
        for (int h = 0; h < 4; h++) {
            #pragma unroll
            for (int off = 8; off; off >>= 1) {
                vs[h] += __shfl_xor(vs[h], off);
                vd[h] += __shfl_xor(vd[h], off);
            }
        }
        if (col == 0) {
            #pragma unroll
            for (int h = 0; h < 4; h++) {
                al_s[n * 4 + h] = vs[h];
                al_d[n * 4 + h] = vd[h];
            }
        }
    }
}

// ---------------- Fused: Layer-1 aggregation + Layer-2 GEMM ----------------
// 1024-thread blocks, 16 nodes/block. Phase 1: wave w aggregates node n0+w
// (online softmax, 4-edge unroll, lane owns 4 channels) -> HE row in LDS
// (stride 264 halves: 16B-aligned, 2-way banks = free). Phase 2: wave 0 runs
// gemm2's 24 MFMAs off the LDS tile -> H2h + al_s2/al_d2. HE values are
// bit-identical to the old HEh path (same fp16 rounding).

__global__ void __launch_bounds__(1024)
k_agg1g2(const __half* __restrict__ H1h, const float* __restrict__ al_s,
         const float* __restrict__ al_d, const int* __restrict__ row_ptr,
         const int* __restrict__ csr_src, const float* __restrict__ b1,
         const uint4* __restrict__ W2f, const float* __restrict__ a_src2,
         const float* __restrict__ a_dst2, __half* __restrict__ H2h,
         float* __restrict__ al_s2, float* __restrict__ al_d2) {
    __shared__ __half he[16][HEP];                    // 16.5 KB
    int w = threadIdx.x >> 6;
    int lane = threadIdx.x & 63;
    int n0 = blockIdx.x * 16;
    {   // ---- phase 1: aggregate node n0+w (one wave per node)
        int n = n0 + w;
        int h = lane >> 4;
        int beg = row_ptr[n], end = row_ptr[n + 1];
        float ald = al_d[n * 4 + h];
        float m = -INFINITY, s = 0.f;
        float a0 = 0.f, a1 = 0.f, a2 = 0.f, a3 = 0.f;
        int j = beg;
        for (; j + 3 < end; j += 4) {
            int ss[4]; float ee[4]; ushort4 hh[4];
            #pragma unroll
            for (int t = 0; t < 4; t++) ss[t] = csr_src[j + t];
            #pragma unroll
            for (int t = 0; t < 4; t++) ee[t] = al_s[ss[t] * 4 + h];
            #pragma unroll
            for (int t = 0; t < 4; t++)
                hh[t] = *(const ushort4*)(H1h + (size_t)ss[t] * C1 + lane * 4);
            #pragma unroll
            for (int t = 0; t < 4; t++) {
                float e = ee[t] + ald;
                ee[t] = (e >= 0.f) ? e : NEG * e;
            }
            float nm = fmaxf(m, fmaxf(fmaxf(ee[0], ee[1]), fmaxf(ee[2], ee[3])));
            float f = __expf(m - nm);
            m = nm;
            float p[4];
            #pragma unroll
            for (int t = 0; t < 4; t++) p[t] = __expf(ee[t] - nm);
            s = s * f + p[0] + p[1] + p[2] + p[3];
            a0 *= f; a1 *= f; a2 *= f; a3 *= f;
            #pragma unroll
            for (int t = 0; t < 4; t++) {
                a0 += p[t] * __half2float(__ushort_as_half(hh[t].x));
                a1 += p[t] * __half2float(__ushort_as_half(hh[t].y));
                a2 += p[t] * __half2float(__ushort_as_half(hh[t].z));
                a3 += p[t] * __half2float(__ushort_as_half(hh[t].w));
            }
        }
        for (; j < end; j++) {
            int s0 = csr_src[j];
            float e = al_s[s0 * 4 + h] + ald;
            e = (e >= 0.f) ? e : NEG * e;
            ushort4 hv = *(const ushort4*)(H1h + (size_t)s0 * C1 + lane * 4);
            float nm = fmaxf(m, e);
            float f  = __expf(m - nm);
            float pr = __expf(e - nm);
            s  = s  * f + pr;
            a0 = a0 * f + pr * __half2float(__ushort_as_half(hv.x));
            a1 = a1 * f + pr * __half2float(__ushort_as_half(hv.y));
            a2 = a2 * f + pr * __half2float(__ushort_as_half(hv.z));
            a3 = a3 * f + pr * __half2float(__ushort_as_half(hv.w));
            m = nm;
        }
        float inv = 1.f / (s + 1e-16f);
        float4 bb = *(const float4*)(b1 + lane * 4);
        float o0 = a0 * inv + bb.x, o1 = a1 * inv + bb.y;
        float o2 = a2 * inv + bb.z, o3 = a3 * inv + bb.w;
        o0 = (o0 > 0.f) ? o0 : expm1f(o0);
        o1 = (o1 > 0.f) ? o1 : expm1f(o1);
        o2 = (o2 > 0.f) ? o2 : expm1f(o2);
        o3 = (o3 > 0.f) ? o3 : expm1f(o3);
        ushort4 pk;
        pk.x = __half_as_ushort(__float2half_rn(o0));
        pk.y = __half_as_ushort(__float2half_rn(o1));
        pk.z = __half_as_ushort(__float2half_rn(o2));
        pk.w = __half_as_ushort(__float2half_rn(o3));
        *(ushort4*)&he[w][lane * 4] = pk;
    }
    __syncthreads();
    if (threadIdx.x < 64) {                           // ---- phase 2: MFMA gemm2 off LDS
        const f16x8* bptr = (const f16x8*)W2f;
        f32x4 acc0 = {0.f, 0.f, 0.f, 0.f};
        f32x4 acc1 = {0.f, 0.f, 0.f, 0.f};
        f32x4 acc2 = {0.f, 0.f, 0.f, 0.f};
        #pragma unroll
        for (int ks = 0; ks < 8; ks++) {
            f16x8 a  = *(const f16x8*)&he[lane & 15][((lane >> 4) << 3) + ks * 32];
            f16x8 b0 = bptr[(0 * 8 + ks) * 64 + lane];
            f16x8 b1 = bptr[(1 * 8 + ks) * 64 + lane];
            f16x8 b2 = bptr[(2 * 8 + ks) * 64 + lane];
            acc0 = __builtin_amdgcn_mfma_f32_16x16x32_f16(a, b0, acc0, 0, 0, 0);
            acc1 = __builtin_amdgcn_mfma_f32_16x16x32_f16(a, b1, acc1, 0, 0, 0);
            acc2 = __builtin_amdgcn_mfma_f32_16x16x32_f16(a, b2, acc2, 0, 0, 0);
        }
        int col = lane & 15;
        int g4  = (lane >> 4) * 4;
        float as[3], ad[3];
        #pragma unroll
        for (int f = 0; f < 3; f++) {
            int c = f * 16 + col;
            as[f] = (c < NCLS) ? a_src2[c] : 0.f;
            ad[f] = (c < NCLS) ? a_dst2[c] : 0.f;
        }
        #pragma unroll
        for (int reg = 0; reg < 4; reg++) {
            int n = n0 + g4 + reg;
            float v0 = acc0[reg], v1 = acc1[reg], v2 = acc2[reg];
            __half* orow = H2h + (size_t)n * H2S;
            orow[col]      = __float2half_rn(v0);
            orow[16 + col] = __float2half_rn(v1);
            orow[32 + col] = __float2half_rn(v2);     // col 47 = pad (zero W2f)
            float vs = v0 * as[0] + v1 * as[1] + v2 * as[2];
            float vd = v0 * ad[0] + v1 * ad[1] + v2 * ad[2];
            #pragma unroll
            for (int off = 8; off; off >>= 1) {
                vs += __shfl_xor(vs, off);
                vd += __shfl_xor(vd, off);
            }
            if (col == 0) { al_s2[n] = vs; al_d2[n] = vd; }
        }
    }
}

// ---------------- Layer 2 aggregation + bias + log_softmax ----------------
// one wave per node; lane<47 owns a class. 4-edge unroll.

__global__ void k_agg2(const __half* __restrict__ H2h, const float* __restrict__ al_s2,
                       const float* __restrict__ al_d2, const int* __restrict__ row_ptr,
                       const int* __restrict__ csr_src, const float* __restrict__ b2,
                       float* __restrict__ out) {
    int n = blockIdx.x * 4 + (threadIdx.x >> 6);
    if (n >= N_NODES) return;
    int lane = threadIdx.x & 63;
    int beg = row_ptr[n], end = row_ptr[n + 1];
    float ald = al_d2[n];
    float m = -INFINITY, s = 0.f, acc = 0.f;
    int j = beg;
    for (; j + 3 < end; j += 4) {
        int ss[4]; float ee[4]; float hv[4];
        #pragma unroll
        for (int t = 0; t < 4; t++) ss[t] = csr_src[j + t];
        #pragma unroll
        for (int t = 0; t < 4; t++) ee[t] = al_s2[ss[t]];
        #pragma unroll
        for (int t = 0; t < 4; t++)
            hv[t] = (lane < NCLS) ? __half2float(H2h[(size_t)ss[t] * H2S + lane]) : 0.f;
        #pragma unroll
        for (int t = 0; t < 4; t++) {
            float e = ee[t] + ald;
            ee[t] = (e >= 0.f) ? e : NEG * e;
        }
        float nm = fmaxf(m, fmaxf(fmaxf(ee[0], ee[1]), fmaxf(ee[2], ee[3])));
        float f = __expf(m - nm);
        m = nm;
        float p[4];
        #pragma unroll
        for (int t = 0; t < 4; t++) p[t] = __expf(ee[t] - nm);
        s = s * f + p[0] + p[1] + p[2] + p[3];
        acc = acc * f + p[0] * hv[0] + p[1] * hv[1] + p[2] * hv[2] + p[3] * hv[3];
    }
    for (; j < end; j++) {
        int src = csr_src[j];
        float e = al_s2[src] + ald;
        e = (e >= 0.f) ? e : NEG * e;
        float hv = (lane < NCLS) ? __half2float(H2h[(size_t)src * H2S + lane]) : 0.f;
        float nm = fmaxf(m, e);
        float f  = __expf(m - nm);
        float pr = __expf(e - nm);
        s   = s   * f + pr;
        acc = acc * f + pr * hv;
        m = nm;
    }
    float v = acc / (s + 1e-16f) + ((lane < NCLS) ? b2[lane] : -INFINITY);
    float mx = v;
    #pragma unroll
    for (int off = 32; off; off >>= 1) mx = fmaxf(mx, __shfl_xor(mx, off));
    float ex = __expf(v - mx);            // lanes >= 47 contribute 0
    float sum = ex;
    #pragma unroll
    for (int off = 32; off; off >>= 1) sum += __shfl_xor(sum, off);
    if (lane < NCLS) out[(size_t)n * NCLS + lane] = v - mx - logf(sum);
}

// ---------------- host ----------------

extern "C" void kernel_launch(void* const* d_in, const int* in_sizes, int n_in,
                              void* d_out, int out_size, void* d_ws, size_t ws_size,
                              hipStream_t stream) {
    const float* x      = (const float*)d_in[0];
    const int*   ei     = (const int*)  d_in[1];
    const float* W1     = (const float*)d_in[2];
    const float* a_src1 = (const float*)d_in[3];
    const float* a_dst1 = (const float*)d_in[4];
    const float* b1     = (const float*)d_in[5];
    const float* W2     = (const float*)d_in[6];
    const float* a_src2 = (const float*)d_in[7];
    const float* a_dst2 = (const float*)d_in[8];
    const float* b2     = (const float*)d_in[9];
    float* out = (float*)d_out;

    char* base = (char*)d_ws;
    size_t off = 0;
    auto alloc = [&](size_t bytes) -> void* {
        void* r = base + off;
        off += (bytes + 511) & ~size_t(511);
        return r;
    };
    __half* H1h   = (__half*)alloc((size_t)N_NODES * C1 * 2);
    __half* H2h   = (__half*)alloc((size_t)N_NODES * H2S * 2);
    __half* xh    = (__half*)alloc((size_t)N_NODES * F_IN * 2);
    uint4*  W1f   = (uint4*) alloc((size_t)4096 * 16);
    uint4*  W2f   = (uint4*) alloc((size_t)1536 * 16);
    float*  al_s1 = (float*) alloc((size_t)N_NODES * 4 * 4);
    float*  al_d1 = (float*) alloc((size_t)N_NODES * 4 * 4);
    float*  al_s2 = (float*) alloc((size_t)N_NODES * 4);
    float*  al_d2 = (float*) alloc((size_t)N_NODES * 4);
    int*    deg   = (int*)   alloc((size_t)N_NODES * 4);
    int*    rowp  = (int*)   alloc((size_t)(N_NODES + 1) * 4);
    int*    cursor= (int*)   alloc((size_t)N_NODES * 4);
    int*    blks  = (int*)   alloc((size_t)SCAN_B * 4);
    int*    blko  = (int*)   alloc((size_t)SCAN_B * 4);
    int*    csrs  = (int*)   alloc((size_t)E_TOT * 4);

    hipMemsetAsync(deg, 0, (size_t)N_NODES * 4, stream);

    k_setup   <<<SB_CNT + SB_PX + SB_W1 + SB_W2, 256, 0, stream>>>(
                  ei, deg, x, xh, W1, W1f, W2, W2f);
    k_scan_blk<<<SCAN_B, 256, 0, stream>>>(deg, blks);
    k_scan_top<<<1, 256, 0, stream>>>(blks, blko);
    k_scan_fin<<<SCAN_B, 256, 0, stream>>>(deg, blko, rowp, cursor);
    k_scatter <<<(E_TOT + 255) / 256, 256, 0, stream>>>(ei, cursor, csrs);

    k_gemm1  <<<N_NODES / 16, 64, 0, stream>>>(xh, W1f, a_src1, a_dst1, H1h, al_s1, al_d1);
    k_agg1g2 <<<N_NODES / 16, 1024, 0, stream>>>(H1h, al_s1, al_d1, rowp, csrs, b1,
                                                 W2f, a_src2, a_dst2, H2h, al_s2, al_d2);
    k_agg2   <<<(N_NODES + 3) / 4, 256, 0, stream>>>(H2h, al_s2, al_d2, rowp, csrs, b2, out);
}